// Round 21
// baseline (21.849 us; speedup 1.0000x reference)
//
#include <hip/hip_runtime.h>
#include <hip/hip_cooperative_groups.h>
#include <math.h>

namespace cg = cooperative_groups;

// QConv2d: x (32,4,64,64) f32, params (4,8,16,16) f32 -> out (32,32,32,32) f32
// B=32 C=4 H=W=64, KH=KW=2 stride 2 -> px=py=32, NW=4, DIM=16, D=8, M=32768
//
// R21: cooperative single-node, grid = EXACTLY 512 blocks (R20's 544 exceeded
// the 2-blocks/CU cooperative co-residency limit -> launch rejected, output
// stayed zero). Blocks 0-31 run prep (PS deg-12 expm -> wfrag) then join the
// regular qconv flow; all 512 blocks B-build pre-sync, grid.sync, MFMA after.
// Host checks occupancy + launch status and falls back to the proven R18
// two-kernel path (same device code, bitwise-identical output).

typedef __attribute__((ext_vector_type(8)))  short bf16x8;   // 8 bf16 (4 VGPR)
typedef __attribute__((ext_vector_type(16))) float f32x16;   // 32x32 MFMA C/D

// RNE float->bf16 (returns low 16 bits)
__device__ __forceinline__ unsigned bfr(float x) {
    unsigned u = __float_as_uint(x);
    return (u + 0x7FFFu + ((u >> 16) & 1u)) >> 16;
}

struct PrepSmem {
    float2 Xs[256], X2[256], X3[256], X4[256], PA[256], PB[256];
    float red[256];
    float srow[16];
    int ssexp;
};

// 16x16 complex matmul stage: D = A*B, ONE trailing barrier.
__device__ __forceinline__ void mm16(float2* D, const float2* A, const float2* B,
                                     int i, int j, int tid) {
    float accr = 0.f, acci = 0.f;
    #pragma unroll
    for (int t = 0; t < 16; ++t) {
        float2 a = A[i * 16 + t], b = B[t * 16 + j];
        accr += a.x * b.x - a.y * b.y;
        acci += a.x * b.y + a.y * b.x;
    }
    D[tid] = make_float2(accr, acci);
    __syncthreads();
}

// D = A*B + (b0*I + b1*X1 + b2*X2 + b3*X3), one trailing barrier.
__device__ __forceinline__ void mm16_addb(float2* D, const float2* A, const float2* B,
                                          const float2* X1, const float2* X2c,
                                          const float2* X3c,
                                          float b0, float b1, float b2, float b3,
                                          int i, int j, int tid) {
    float accr = 0.f, acci = 0.f;
    #pragma unroll
    for (int t = 0; t < 16; ++t) {
        float2 a = A[i * 16 + t], b = B[t * 16 + j];
        accr += a.x * b.x - a.y * b.y;
        acci += a.x * b.y + a.y * b.x;
    }
    float2 v1 = X1[tid], v2 = X2c[tid], v3 = X3c[tid];
    float idd = (i == j) ? 1.f : 0.f;
    accr += b0 * idd + b1 * v1.x + b2 * v2.x + b3 * v3.x;
    acci +=            b1 * v1.y + b2 * v2.y + b3 * v3.y;
    D[tid] = make_float2(accr, acci);
    __syncthreads();
}

// Fast acos: A&S 4.4.45, |abs err| <= 6.8e-5 over [-1,1]
__device__ __forceinline__ float acos_fast(float t) {
    float ax = fabsf(t);
    float p = fmaf(ax, -0.0187293f, 0.0742610f);
    p = fmaf(ax, p, -0.2121144f);
    p = fmaf(ax, p, 1.5707288f);
    float f = sqrtf(1.0f - ax) * p;
    return (t >= 0.f) ? f : (3.14159265358979f - f);
}

// ---------------- prep body: expm(SH) -> bf16 A-fragments (one block = one cd)
// W'[j][k] = expm(SH)[k][j] * (-i)^popc(k); A-frag for mfma_f32_32x32x16_bf16:
// rows 0-15 Re W', rows 16-31 Im W'; row=lane&31, k=(lane>>5)*8+e; bf16 hi.
__device__ __forceinline__ void prep_body(PrepSmem& sm,
                                          const float* __restrict__ params,
                                          unsigned* __restrict__ wfrag,
                                          int bid, int tid) {
    const int i = tid >> 4, j = tid & 15;

    const float* pm = params + bid * 256;
    float pij = pm[i * 16 + j];
    float pji = pm[j * 16 + i];
    float ar = pij - pji;   // asym -> real part of SH
    float ai = pij + pji;   // sym  -> imag part of SH
    sm.red[tid] = fabsf(ar) + fabsf(ai);
    __syncthreads();
    if (j == 0) {
        float s = 0.f;
        for (int t = 0; t < 16; ++t) s += sm.red[i * 16 + t];
        sm.srow[i] = s;
    }
    __syncthreads();
    if (tid == 0) {
        float mx = 0.f;
        for (int t = 0; t < 16; ++t) mx = fmaxf(mx, sm.srow[t]);
        int se = 0;
        while (mx > 1.0f && se < 40) { mx *= 0.5f; se++; }
        sm.ssexp = se;
    }
    __syncthreads();
    const int sexp = sm.ssexp;
    const float scale = exp2f((float)(-sexp));
    sm.Xs[tid] = make_float2(ar * scale, ai * scale);
    __syncthreads();

    mm16(sm.X2, sm.Xs, sm.Xs, i, j, tid);
    mm16(sm.X3, sm.X2, sm.Xs, i, j, tid);
    mm16(sm.X4, sm.X2, sm.X2, i, j, tid);

    {   // P2' = c8 I + c9 X + c10 X2 + c11 X3 + c12 X4 -> PA (elementwise)
        const float c8 = 2.4801587e-5f, c9 = 2.7557319e-6f, c10 = 2.7557319e-7f,
                    c11 = 2.5052108e-8f, c12 = 2.0876757e-9f;
        float2 v1 = sm.Xs[tid], v2 = sm.X2[tid], v3 = sm.X3[tid], v4 = sm.X4[tid];
        float idd = (i == j) ? 1.f : 0.f;
        sm.PA[tid] = make_float2(c8 * idd + c9 * v1.x + c10 * v2.x + c11 * v3.x + c12 * v4.x,
                                 c9 * v1.y + c10 * v2.y + c11 * v3.y + c12 * v4.y);
        __syncthreads();
    }
    mm16_addb(sm.PB, sm.X4, sm.PA, sm.Xs, sm.X2, sm.X3,
              4.1666667e-2f, 8.3333333e-3f, 1.3888889e-3f, 1.9841270e-4f, i, j, tid);
    mm16_addb(sm.PA, sm.X4, sm.PB, sm.Xs, sm.X2, sm.X3,
              1.f, 1.f, 0.5f, 1.6666667e-1f, i, j, tid);

    float2* cur = sm.PA;
    float2* nxt = sm.PB;
    for (int sq = 0; sq < sexp; ++sq) {
        float accr = 0.f, acci = 0.f;
        #pragma unroll
        for (int t = 0; t < 16; ++t) {
            float2 a = cur[i * 16 + t], b = cur[t * 16 + j];
            accr += a.x * b.x - a.y * b.y;
            acci += a.x * b.y + a.y * b.x;
        }
        nxt[tid] = make_float2(accr, acci);
        __syncthreads();
        float2* tmp = cur; cur = nxt; nxt = tmp;
    }

    // W'[j][i] = U[i][j]*(-i)^popc(i), stash into Xs (stale after powers)
    float2 e = cur[tid];
    int pc = __popc(i) & 3;
    float2 o;
    if (pc == 0)      o = make_float2( e.x,  e.y);
    else if (pc == 1) o = make_float2( e.y, -e.x);
    else if (pc == 2) o = make_float2(-e.x, -e.y);
    else              o = make_float2(-e.y,  e.x);
    sm.Xs[(tid & 15) * 16 + (tid >> 4)] = o;
    __syncthreads();

    {   // A-fragment emit: lane = tid&63, pr = tid>>6 (elements 2pr, 2pr+1)
        const int lane = tid & 63;
        const int pr = tid >> 6;
        const int row = lane & 31;      // 0-15: Re rows, 16-31: Im rows
        const int kh = lane >> 5;
        const int k0 = kh * 8 + pr * 2;
        float v0, v1;
        if (row < 16) { v0 = sm.Xs[row * 16 + k0].x; v1 = sm.Xs[row * 16 + k0 + 1].x; }
        else          { v0 = sm.Xs[(row - 16) * 16 + k0].y; v1 = sm.Xs[(row - 16) * 16 + k0 + 1].y; }
        unsigned base = (unsigned)(bid * 64 + lane) * 4u;
        wfrag[base + pr] = bfr(v0) | (bfr(v1) << 16);
    }
}

// ---------------- qconv part 1: x-load + trig + B fragments (pre-sync) ------
__device__ __forceinline__ void qconv_build(const float* __restrict__ x,
                                            int blkid, int tid,
                                            bf16x8 (&bhi)[4], bf16x8 (&blo)[4],
                                            int& lane, int& hi, int& dh,
                                            int& b, int& ix, int& iy) {
    lane = tid & 63;
    const int s = lane & 31;
    hi = lane >> 5;
    const int wave = blkid * 4 + (tid >> 6);   // 0..2047
    const int msite = wave >> 1;               // 0..1023
    dh = wave & 1;
    const int m = msite * 32 + s;
    b = m >> 10; ix = (m >> 5) & 31; iy = m & 31;

    #pragma unroll
    for (int c = 0; c < 4; ++c) {
        const float* xc = x + (((b * 4 + c) * 64 + 2 * ix) * 64 + 2 * iy);
        float2 xa = *(const float2*)xc;         // theta0, theta1 (row 2ix)
        float2 xb = *(const float2*)(xc + 64);  // theta2, theta3 (row 2ix+1)
        float sn0, cs0, sn1, cs1, sn2, cs2, sn3, cs3;
        __sincosf(xa.x * 0.5f, &sn0, &cs0);
        __sincosf(xa.y * 0.5f, &sn1, &cs1);
        __sincosf(xb.x * 0.5f, &sn2, &cs2);
        __sincosf(xb.y * 0.5f, &sn3, &cs3);
        float f0 = hi ? sn0 : cs0;              // k bit3 = hi (wire0)
        float g0 = f0 * cs1, g1 = f0 * sn1;
        float h0 = g0 * cs2, h1 = g0 * sn2, h2 = g1 * cs2, h3 = g1 * sn2;
        float r[8];
        r[0] = h0 * cs3; r[1] = h0 * sn3; r[2] = h1 * cs3; r[3] = h1 * sn3;
        r[4] = h2 * cs3; r[5] = h2 * sn3; r[6] = h3 * cs3; r[7] = h3 * sn3;
        #pragma unroll
        for (int e = 0; e < 8; ++e) {
            unsigned hb = bfr(r[e]);
            bhi[c][e] = (short)hb;
            blo[c][e] = (short)bfr(r[e] - __uint_as_float(hb << 16));
        }
    }
}

// ---------------- qconv part 2: wf loads + MFMA + Walsh + acos + store ------
__device__ __forceinline__ void qconv_mfma(const unsigned* __restrict__ wfrag,
                                           float* __restrict__ out,
                                           const bf16x8 (&bhi)[4], const bf16x8 (&blo)[4],
                                           int lane, int hi, int dh,
                                           int b, int ix, int iy) {
    const bf16x8* wf = (const bf16x8*)wfrag;
    bf16x8 wfr[16];
    #pragma unroll
    for (int dd = 0; dd < 4; ++dd)
        #pragma unroll
        for (int c = 0; c < 4; ++c)
            wfr[dd * 4 + c] = wf[(c * 8 + dh * 4 + dd) * 64 + lane];

    const float sgn1 = hi ? -1.f : 1.f;   // w=1 partial sign (bit2 of j = hi)
    const f32x16 z = {0.f,0.f,0.f,0.f,0.f,0.f,0.f,0.f,
                      0.f,0.f,0.f,0.f,0.f,0.f,0.f,0.f};

    #pragma unroll
    for (int dd = 0; dd < 4; ++dd) {
        const int d = dh * 4 + dd;
        float accA = 0.f, accB = 0.f;
        #pragma unroll
        for (int c = 0; c < 4; ++c) {
            bf16x8 ahi = wfr[dd * 4 + c];
            f32x16 acc = __builtin_amdgcn_mfma_f32_32x32x16_bf16(ahi, blo[c], z, 0, 0, 0);
            acc = __builtin_amdgcn_mfma_f32_32x32x16_bf16(ahi, bhi[c], acc, 0, 0, 0);
            // lane holds j = hi*4 + (i&3) + 8*(i>>2): yr = acc[i], yi = acc[8+i]
            float q[8];
            #pragma unroll
            for (int i = 0; i < 8; ++i)
                q[i] = fmaf(acc[i], acc[i], acc[8 + i] * acc[8 + i]);
            float e01 = q[0] + q[1], o01 = q[0] - q[1];
            float e23 = q[2] + q[3], o23 = q[2] - q[3];
            float e45 = q[4] + q[5], o45 = q[4] - q[5];
            float e67 = q[6] + q[7], o67 = q[6] - q[7];
            float A  = e01 + e23, B2a = e01 - e23, A3a = o01 + o23;
            float C  = e45 + e67, B2b = e45 - e67, A3b = o45 + o67;
            float S   = A + C;
            float pw0 = A - C;          // bit3 sign (i>>2)
            float pw1 = sgn1 * S;       // bit2 sign (hi, lane-uniform)
            float pw2 = B2a + B2b;      // bit1 sign
            float pw3 = A3a + A3b;      // bit0 sign
            float sendA = hi ? pw0 : pw2, myA = hi ? pw2 : pw0;
            float sendB = hi ? pw1 : pw3, myB = hi ? pw3 : pw1;
            float tA = myA + __shfl_xor(sendA, 32);
            float tB = myB + __shfl_xor(sendB, 32);
            tA = fminf(fmaxf(tA, -1.f), 1.f);
            tB = fminf(fmaxf(tB, -1.f), 1.f);
            accA += acos_fast(tA);
            accB += acos_fast(tB);
        }
        float* ob = out + ((b * 32 + d * 4 + 2 * hi) * 32 + ix) * 32 + iy;
        ob[0]    = accA;
        ob[1024] = accB;
    }
}

// ---------------- cooperative fused kernel (512 blocks) ----------------------
__global__ __launch_bounds__(256)
__attribute__((amdgpu_waves_per_eu(2, 4)))
void fused_kernel(const float* __restrict__ x,
                  const float* __restrict__ params,
                  unsigned* __restrict__ wfrag,
                  float* __restrict__ out) {
    __shared__ PrepSmem sm;
    const int tid = threadIdx.x;

    if (blockIdx.x < 32) {
        prep_body(sm, params, wfrag, blockIdx.x, tid);
        __threadfence();
    }

    int lane, hi, dh, b, ix, iy;
    bf16x8 bhi[4], blo[4];
    qconv_build(x, blockIdx.x, tid, bhi, blo, lane, hi, dh, b, ix, iy);

    cg::this_grid().sync();   // wfrag ready

    qconv_mfma(wfrag, out, bhi, blo, lane, hi, dh, b, ix, iy);
}

// ---------------- fallback two-kernel path (R18-proven) ----------------------
__global__ __launch_bounds__(256) void prep_kernel(const float* __restrict__ params,
                                                   unsigned* __restrict__ wfrag) {
    __shared__ PrepSmem sm;
    prep_body(sm, params, wfrag, blockIdx.x, threadIdx.x);
}

__global__ __launch_bounds__(256)
__attribute__((amdgpu_waves_per_eu(2, 4)))
void qconv_kernel(const float* __restrict__ x,
                  const unsigned* __restrict__ wfrag,
                  float* __restrict__ out) {
    int lane, hi, dh, b, ix, iy;
    bf16x8 bhi[4], blo[4];
    qconv_build(x, blockIdx.x, threadIdx.x, bhi, blo, lane, hi, dh, b, ix, iy);
    qconv_mfma(wfrag, out, bhi, blo, lane, hi, dh, b, ix, iy);
}

extern "C" void kernel_launch(void* const* d_in, const int* in_sizes, int n_in,
                              void* d_out, int out_size, void* d_ws, size_t ws_size,
                              hipStream_t stream) {
    const float* x = (const float*)d_in[0];
    const float* params = (const float*)d_in[1];
    float* out = (float*)d_out;
    unsigned* wfrag = (unsigned*)d_ws;   // 32 cd * 64 lanes * 16 B = 32 KiB

    // capture-safe host-side occupancy check: coop needs all 512 blocks resident
    int blocksPerCU = 0;
    hipError_t qerr = hipOccupancyMaxActiveBlocksPerMultiprocessor(
        &blocksPerCU, (const void*)fused_kernel, 256, 0);
    bool coop = (qerr == hipSuccess) && (blocksPerCU * 256 >= 512);

    if (coop) {
        void* args[] = {(void*)&x, (void*)&params, (void*)&wfrag, (void*)&out};
        hipError_t lerr = hipLaunchCooperativeKernel((void*)fused_kernel, dim3(512),
                                                     dim3(256), args, 0, stream);
        coop = (lerr == hipSuccess);
    }
    if (!coop) {
        // bitwise-identical two-node fallback (same device code)
        prep_kernel<<<32, 256, 0, stream>>>(params, wfrag);
        qconv_kernel<<<512, 256, 0, stream>>>(x, wfrag, out);
    }
}

// Round 22
// 21.599 us; speedup vs baseline: 1.0116x; 1.0116x over previous
//
#include <hip/hip_runtime.h>
#include <math.h>

// QConv2d: x (32,4,64,64) f32, params (4,8,16,16) f32 -> out (32,32,32,32) f32
// B=32 C=4 H=W=64, KH=KW=2 stride 2 -> px=py=32, NW=4, DIM=16, D=8, M=32768
//
// R22 = R18 two-node structure (best measured: 21.5us; coop fusion R21 was
// neutral) + v_cvt_pk_bf16_f32 packing in qconv's B-build (saves ~240
// VALU inst/wave vs scalar bfr; RNE -> bitwise-identical results).

typedef __attribute__((ext_vector_type(8)))  short bf16x8;   // 8 bf16 (4 VGPR)
typedef __attribute__((ext_vector_type(16))) float f32x16;   // 32x32 MFMA C/D
typedef __attribute__((ext_vector_type(4)))  unsigned u32x4;

union pk_u { u32x4 u; bf16x8 s; };

// RNE float->bf16 (returns low 16 bits) - prep only
__device__ __forceinline__ unsigned bfr(float x) {
    unsigned u = __float_as_uint(x);
    return (u + 0x7FFFu + ((u >> 16) & 1u)) >> 16;
}

// packed RNE bf16 pair: lo half = bf16(a), hi half = bf16(b)
__device__ __forceinline__ unsigned cvt_pk(float a, float b) {
    unsigned r;
    asm("v_cvt_pk_bf16_f32 %0, %1, %2" : "=v"(r) : "v"(a), "v"(b));
    return r;
}

struct PrepSmem {
    float2 Xs[256], X2[256], X3[256], X4[256], PA[256], PB[256];
    float red[256];
    float srow[16];
    int ssexp;
};

// 16x16 complex matmul stage: D = A*B, ONE trailing barrier.
__device__ __forceinline__ void mm16(float2* D, const float2* A, const float2* B,
                                     int i, int j, int tid) {
    float accr = 0.f, acci = 0.f;
    #pragma unroll
    for (int t = 0; t < 16; ++t) {
        float2 a = A[i * 16 + t], b = B[t * 16 + j];
        accr += a.x * b.x - a.y * b.y;
        acci += a.x * b.y + a.y * b.x;
    }
    D[tid] = make_float2(accr, acci);
    __syncthreads();
}

// D = A*B + (b0*I + b1*X1 + b2*X2 + b3*X3), one trailing barrier.
__device__ __forceinline__ void mm16_addb(float2* D, const float2* A, const float2* B,
                                          const float2* X1, const float2* X2c,
                                          const float2* X3c,
                                          float b0, float b1, float b2, float b3,
                                          int i, int j, int tid) {
    float accr = 0.f, acci = 0.f;
    #pragma unroll
    for (int t = 0; t < 16; ++t) {
        float2 a = A[i * 16 + t], b = B[t * 16 + j];
        accr += a.x * b.x - a.y * b.y;
        acci += a.x * b.y + a.y * b.x;
    }
    float2 v1 = X1[tid], v2 = X2c[tid], v3 = X3c[tid];
    float idd = (i == j) ? 1.f : 0.f;
    accr += b0 * idd + b1 * v1.x + b2 * v2.x + b3 * v3.x;
    acci +=            b1 * v1.y + b2 * v2.y + b3 * v3.y;
    D[tid] = make_float2(accr, acci);
    __syncthreads();
}

// Fast acos: A&S 4.4.45, |abs err| <= 6.8e-5 over [-1,1]
__device__ __forceinline__ float acos_fast(float t) {
    float ax = fabsf(t);
    float p = fmaf(ax, -0.0187293f, 0.0742610f);
    p = fmaf(ax, p, -0.2121144f);
    p = fmaf(ax, p, 1.5707288f);
    float f = sqrtf(1.0f - ax) * p;
    return (t >= 0.f) ? f : (3.14159265358979f - f);
}

// ---------------- prep body: expm(SH) -> bf16 A-fragments (one block = one cd)
// W'[j][k] = expm(SH)[k][j] * (-i)^popc(k); A-frag for mfma_f32_32x32x16_bf16:
// rows 0-15 Re W', rows 16-31 Im W'; row=lane&31, k=(lane>>5)*8+e; bf16 hi.
// Paterson-Stockmeyer deg-12 + scale/square: 11 stages, 1 barrier each.
__device__ __forceinline__ void prep_body(PrepSmem& sm,
                                          const float* __restrict__ params,
                                          unsigned* __restrict__ wfrag,
                                          int bid, int tid) {
    const int i = tid >> 4, j = tid & 15;

    const float* pm = params + bid * 256;
    float pij = pm[i * 16 + j];
    float pji = pm[j * 16 + i];
    float ar = pij - pji;   // asym -> real part of SH
    float ai = pij + pji;   // sym  -> imag part of SH
    sm.red[tid] = fabsf(ar) + fabsf(ai);
    __syncthreads();
    if (j == 0) {
        float s = 0.f;
        for (int t = 0; t < 16; ++t) s += sm.red[i * 16 + t];
        sm.srow[i] = s;
    }
    __syncthreads();
    if (tid == 0) {
        float mx = 0.f;
        for (int t = 0; t < 16; ++t) mx = fmaxf(mx, sm.srow[t]);
        int se = 0;
        while (mx > 1.0f && se < 40) { mx *= 0.5f; se++; }
        sm.ssexp = se;
    }
    __syncthreads();
    const int sexp = sm.ssexp;
    const float scale = exp2f((float)(-sexp));
    sm.Xs[tid] = make_float2(ar * scale, ai * scale);
    __syncthreads();

    mm16(sm.X2, sm.Xs, sm.Xs, i, j, tid);
    mm16(sm.X3, sm.X2, sm.Xs, i, j, tid);
    mm16(sm.X4, sm.X2, sm.X2, i, j, tid);

    {   // P2' = c8 I + c9 X + c10 X2 + c11 X3 + c12 X4 -> PA (elementwise)
        const float c8 = 2.4801587e-5f, c9 = 2.7557319e-6f, c10 = 2.7557319e-7f,
                    c11 = 2.5052108e-8f, c12 = 2.0876757e-9f;
        float2 v1 = sm.Xs[tid], v2 = sm.X2[tid], v3 = sm.X3[tid], v4 = sm.X4[tid];
        float idd = (i == j) ? 1.f : 0.f;
        sm.PA[tid] = make_float2(c8 * idd + c9 * v1.x + c10 * v2.x + c11 * v3.x + c12 * v4.x,
                                 c9 * v1.y + c10 * v2.y + c11 * v3.y + c12 * v4.y);
        __syncthreads();
    }
    mm16_addb(sm.PB, sm.X4, sm.PA, sm.Xs, sm.X2, sm.X3,
              4.1666667e-2f, 8.3333333e-3f, 1.3888889e-3f, 1.9841270e-4f, i, j, tid);
    mm16_addb(sm.PA, sm.X4, sm.PB, sm.Xs, sm.X2, sm.X3,
              1.f, 1.f, 0.5f, 1.6666667e-1f, i, j, tid);

    float2* cur = sm.PA;
    float2* nxt = sm.PB;
    for (int sq = 0; sq < sexp; ++sq) {
        float accr = 0.f, acci = 0.f;
        #pragma unroll
        for (int t = 0; t < 16; ++t) {
            float2 a = cur[i * 16 + t], b = cur[t * 16 + j];
            accr += a.x * b.x - a.y * b.y;
            acci += a.x * b.y + a.y * b.x;
        }
        nxt[tid] = make_float2(accr, acci);
        __syncthreads();
        float2* tmp = cur; cur = nxt; nxt = tmp;
    }

    // W'[j][i] = U[i][j]*(-i)^popc(i), stash into Xs (stale after powers)
    float2 e = cur[tid];
    int pc = __popc(i) & 3;
    float2 o;
    if (pc == 0)      o = make_float2( e.x,  e.y);
    else if (pc == 1) o = make_float2( e.y, -e.x);
    else if (pc == 2) o = make_float2(-e.x, -e.y);
    else              o = make_float2(-e.y,  e.x);
    sm.Xs[(tid & 15) * 16 + (tid >> 4)] = o;
    __syncthreads();

    {   // A-fragment emit: lane = tid&63, pr = tid>>6 (elements 2pr, 2pr+1)
        const int lane = tid & 63;
        const int pr = tid >> 6;
        const int row = lane & 31;      // 0-15: Re rows, 16-31: Im rows
        const int kh = lane >> 5;
        const int k0 = kh * 8 + pr * 2;
        float v0, v1;
        if (row < 16) { v0 = sm.Xs[row * 16 + k0].x; v1 = sm.Xs[row * 16 + k0 + 1].x; }
        else          { v0 = sm.Xs[(row - 16) * 16 + k0].y; v1 = sm.Xs[(row - 16) * 16 + k0 + 1].y; }
        unsigned base = (unsigned)(bid * 64 + lane) * 4u;
        wfrag[base + pr] = bfr(v0) | (bfr(v1) << 16);
    }
}

__global__ __launch_bounds__(256) void prep_kernel(const float* __restrict__ params,
                                                   unsigned* __restrict__ wfrag) {
    __shared__ PrepSmem sm;
    prep_body(sm, params, wfrag, blockIdx.x, threadIdx.x);
}

// ---------------- Kernel 2: 32x32x16 MFMA main compute -----------------------
// Wave = 32 sites (site = lane&31, hi = lane>>5) x 4 d's (dh = wave&1).
// Operand prefetch: x loads first, then all 16 wf fragments (their L3/L2
// latency hides under the trig B-build). Per (c,d): Y = [Re W'; Im W'](bf16)
// x r via 2 MFMAs (Ahi*blo + Ahi*bhi, fp32 accum; b-split keeps r near-exact).
// C layout (HW-verified): col=lane&31=site, row=(reg&3)+8*(reg>>2)+4*hi ->
// yr/yi in-lane; Walsh partials in-lane; one hi<->lo shfl pair per (c,d);
// 2 acos/lane/cd; plain store, written exactly once. B-pack via
// v_cvt_pk_bf16_f32 (1 inst/pair vs ~10 for scalar bfr; same RNE bits).
__global__ __launch_bounds__(256)
__attribute__((amdgpu_waves_per_eu(2, 4)))
void qconv_kernel(const float* __restrict__ x,
                  const unsigned* __restrict__ wfrag,
                  float* __restrict__ out) {
    const int tid = threadIdx.x;
    const int lane = tid & 63;
    const int s = lane & 31;
    const int hi = lane >> 5;
    const int wave = blockIdx.x * 4 + (tid >> 6);   // 0..2047
    const int msite = wave >> 1;                    // 0..1023
    const int dh = wave & 1;
    const int m = msite * 32 + s;
    const int b = m >> 10, ix = (m >> 5) & 31, iy = m & 31;

    const bf16x8* wf = (const bf16x8*)wfrag;

    // 1) x loads first
    float2 xa[4], xb[4];
    #pragma unroll
    for (int c = 0; c < 4; ++c) {
        const float* xc = x + (((b * 4 + c) * 64 + 2 * ix) * 64 + 2 * iy);
        xa[c] = *(const float2*)xc;         // theta0, theta1 (row 2ix)
        xb[c] = *(const float2*)(xc + 64);  // theta2, theta3 (row 2ix+1)
    }
    // 2) all wf fragment loads; latency covered by trig below
    bf16x8 wfr[16];
    #pragma unroll
    for (int dd = 0; dd < 4; ++dd)
        #pragma unroll
        for (int c = 0; c < 4; ++c)
            wfr[dd * 4 + c] = wf[(c * 8 + dh * 4 + dd) * 64 + lane];

    // 3) B fragments (r, 16xK x 32 sites): col=site, k=hi*8+e; split bf16
    bf16x8 bhi[4], blo[4];
    #pragma unroll
    for (int c = 0; c < 4; ++c) {
        float sn0, cs0, sn1, cs1, sn2, cs2, sn3, cs3;
        __sincosf(xa[c].x * 0.5f, &sn0, &cs0);
        __sincosf(xa[c].y * 0.5f, &sn1, &cs1);
        __sincosf(xb[c].x * 0.5f, &sn2, &cs2);
        __sincosf(xb[c].y * 0.5f, &sn3, &cs3);
        float f0 = hi ? sn0 : cs0;              // k bit3 = hi (wire0)
        float g0 = f0 * cs1, g1 = f0 * sn1;
        float h0 = g0 * cs2, h1 = g0 * sn2, h2 = g1 * cs2, h3 = g1 * sn2;
        float r[8];
        r[0] = h0 * cs3; r[1] = h0 * sn3; r[2] = h1 * cs3; r[3] = h1 * sn3;
        r[4] = h2 * cs3; r[5] = h2 * sn3; r[6] = h3 * cs3; r[7] = h3 * sn3;
        pk_u uh, ul;
        #pragma unroll
        for (int p = 0; p < 4; ++p) {
            float rA = r[2 * p], rB = r[2 * p + 1];
            unsigned wh = cvt_pk(rA, rB);
            float hA = __uint_as_float(wh << 16);
            float hB = __uint_as_float(wh & 0xFFFF0000u);
            uh.u[p] = wh;
            ul.u[p] = cvt_pk(rA - hA, rB - hB);
        }
        bhi[c] = uh.s;
        blo[c] = ul.s;
    }

    const float sgn1 = hi ? -1.f : 1.f;   // w=1 partial sign (bit2 of j = hi)
    const f32x16 z = {0.f,0.f,0.f,0.f,0.f,0.f,0.f,0.f,
                      0.f,0.f,0.f,0.f,0.f,0.f,0.f,0.f};

    // 4) main loop, fully unrolled (wfr indices compile-time)
    #pragma unroll
    for (int dd = 0; dd < 4; ++dd) {
        const int d = dh * 4 + dd;
        float accA = 0.f, accB = 0.f;
        #pragma unroll
        for (int c = 0; c < 4; ++c) {
            bf16x8 ahi = wfr[dd * 4 + c];
            f32x16 acc = __builtin_amdgcn_mfma_f32_32x32x16_bf16(ahi, blo[c], z, 0, 0, 0);
            acc = __builtin_amdgcn_mfma_f32_32x32x16_bf16(ahi, bhi[c], acc, 0, 0, 0);
            // lane holds j = hi*4 + (i&3) + 8*(i>>2): yr = acc[i], yi = acc[8+i]
            float q[8];
            #pragma unroll
            for (int i = 0; i < 8; ++i)
                q[i] = fmaf(acc[i], acc[i], acc[8 + i] * acc[8 + i]);
            // in-lane Walsh partials (4 w) over the 8 j's
            float e01 = q[0] + q[1], o01 = q[0] - q[1];
            float e23 = q[2] + q[3], o23 = q[2] - q[3];
            float e45 = q[4] + q[5], o45 = q[4] - q[5];
            float e67 = q[6] + q[7], o67 = q[6] - q[7];
            float A  = e01 + e23, B2a = e01 - e23, A3a = o01 + o23;
            float C  = e45 + e67, B2b = e45 - e67, A3b = o45 + o67;
            float S   = A + C;
            float pw0 = A - C;          // bit3 sign (i>>2)
            float pw1 = sgn1 * S;       // bit2 sign (hi, lane-uniform)
            float pw2 = B2a + B2b;      // bit1 sign
            float pw3 = A3a + A3b;      // bit0 sign
            // one hi<->lo exchange: hi=0 finalizes w0,w1; hi=1 finalizes w2,w3
            float sendA = hi ? pw0 : pw2, myA = hi ? pw2 : pw0;
            float sendB = hi ? pw1 : pw3, myB = hi ? pw3 : pw1;
            float tA = myA + __shfl_xor(sendA, 32);
            float tB = myB + __shfl_xor(sendB, 32);
            tA = fminf(fmaxf(tA, -1.f), 1.f);
            tB = fminf(fmaxf(tB, -1.f), 1.f);
            accA += acos_fast(tA);
            accB += acos_fast(tB);
        }
        // out[b][d*4 + 2*hi + {0,1}][ix][iy] - written exactly once
        float* ob = out + ((b * 32 + d * 4 + 2 * hi) * 32 + ix) * 32 + iy;
        ob[0]    = accA;
        ob[1024] = accB;
    }
}

extern "C" void kernel_launch(void* const* d_in, const int* in_sizes, int n_in,
                              void* d_out, int out_size, void* d_ws, size_t ws_size,
                              hipStream_t stream) {
    const float* x = (const float*)d_in[0];
    const float* params = (const float*)d_in[1];
    float* out = (float*)d_out;
    unsigned* wfrag = (unsigned*)d_ws;   // 32 cd * 64 lanes * 16 B = 32 KiB

    prep_kernel<<<32, 256, 0, stream>>>(params, wfrag);
    qconv_kernel<<<512, 256, 0, stream>>>(x, wfrag, out);
}